// Round 24
// baseline (187.811 us; speedup 1.0000x reference)
//
#include <hip/hip_runtime.h>

typedef __bf16 bf16;
typedef bf16 bf16x8 __attribute__((ext_vector_type(8)));
typedef bf16 bf16x4 __attribute__((ext_vector_type(4)));
typedef float floatx4 __attribute__((ext_vector_type(4)));

#define D_MODEL 1024
#define SEQ     2048
#define NB      4
#define NH      16
#define DKH     64
// log2(10000)/32
#define ROPE_L2 0.4152410118609203f

__device__ __forceinline__ floatx4 mfma16(bf16x8 a, bf16x8 b, floatx4 c) {
  return __builtin_amdgcn_mfma_f32_16x16x32_bf16(a, b, c, 0, 0, 0);
}

// Async global->LDS, 16B per lane. lds base must be wave-uniform; HW adds lane*16.
__device__ __forceinline__ void gload_lds16(void* lds_uniform, const void* gsrc) {
  __builtin_amdgcn_global_load_lds(
      (__attribute__((address_space(1))) unsigned int*)(void*)(gsrc),
      (__attribute__((address_space(3))) unsigned int*)lds_uniform,
      16, 0, 0);
}

// ------- fused prep: fp32->bf16 (x + 4 weights) AND RoPE table, ONE launch -------
__global__ __launch_bounds__(256) void cvt_all(
    const float4* __restrict__ x,
    const float4* __restrict__ wq, const float4* __restrict__ wk,
    const float4* __restrict__ wv, const float4* __restrict__ wo,
    bf16x4* __restrict__ xb,
    bf16x4* __restrict__ b0, bf16x4* __restrict__ b1,
    bf16x4* __restrict__ b2, bf16x4* __restrict__ b3,
    const int* __restrict__ tokpos, float2* __restrict__ ropetab) {
  const int i = blockIdx.x * 256 + threadIdx.x;
  if (i < (1 << 21) + (1 << 20)) {
    const float4* src;
    bf16x4* dst;
    int off;
    if (i < (1 << 21)) {
      src = x; dst = xb; off = i;
    } else {
      const int j = i - (1 << 21);
      const int widx = j >> 18;
      off = j & ((1 << 18) - 1);
      src = (widx == 0) ? wq : (widx == 1) ? wk : (widx == 2) ? wv : wo;
      dst = (widx == 0) ? b0 : (widx == 1) ? b1 : (widx == 2) ? b2 : b3;
    }
    const float4 v = src[off];
    bf16x4 o;
    o[0] = (bf16)v.x; o[1] = (bf16)v.y; o[2] = (bf16)v.z; o[3] = (bf16)v.w;
    dst[off] = o;
  } else {
    const int k = i - (1 << 21) - (1 << 20);  // [0, 65536)
    const int s = k >> 5, i2 = k & 31;
    const float ang = (float)tokpos[s] * exp2f(-(float)i2 * ROPE_L2);
    float sn, cs;
    sincosf(ang, &sn, &cs);
    ropetab[k] = make_float2(sn, cs);
  }
}

// =============== merged projection kernel ===============
// R24: QK-fused path split to BN=64 (one head per block) -> 1024 QK blocks
// (R23 had 512 = 2/CU; latency-bound at 27% MfmaUtil). AI drops 0.56->0.75
// KB-LDS/MFMA (ceiling 55->42%) but blocks/CU double and LDS drops to 32KB
// (5 blocks admissible). V path unchanged; flat 1536-block grid interleaves
// QK:V = 2:1 so every XCD chunk gets the same mix (V backfills QK).

// ---- QK64 path: two C(128x64) = A@Wq^T, A@Wk^T. LDS/buf: A 8K | Bq 4K | Bk 4K.
#define QK64A(buf) ((char*)LDSBUF + (buf) * 16384)
#define QK64Q(buf) ((char*)LDSBUF + (buf) * 16384 + 8192)
#define QK64K(buf) ((char*)LDSBUF + (buf) * 16384 + 12288)

#define QK64_STAGE(buf, kk)                                                    \
  gload_lds16(QK64A(buf) + (w * 64) * 16, asrc0 + (kk));                       \
  gload_lds16(QK64A(buf) + (w * 64 + 256) * 16, asrc1 + (kk));                 \
  gload_lds16(QK64Q(buf) + (w * 64) * 16, bqsrc + (kk));                       \
  gload_lds16(QK64K(buf) + (w * 64) * 16, bksrc + (kk));

// RoPE + bounce write for one 16x16 frag (pass-local 64-row coords; BN=64 ->
// col == d, one head per block).
#define ROPEW64(mm, nn, CV, SC)                                                \
  _Pragma("unroll")                                                            \
  for (int reg = 0; reg < 4; ++reg) {                                          \
    const int srow = mm * 16 + g * 4 + reg;                                    \
    const int col = wc * 32 + nn * 16 + r;                                     \
    const int s_ = (bm + p * 64 + srow) & (SEQ - 1);                           \
    float v = CV[reg];                                                         \
    float pp = __shfl_xor(v, 1);                                               \
    const float2 sc2 = ropetab[s_ * 32 + (col >> 1)];                          \
    float res = ((col & 1) == 0) ? (sc2.y * v - sc2.x * pp)                    \
                                 : (sc2.x * pp + sc2.y * v);                   \
    res *= SC;                                                                 \
    *(bf16*)((char*)LDSBUF + srow * 272 + col * 2) = (bf16)res;                \
  }

// Bounce+store one output (Q or K): 2 passes of 64 rows; 128B contiguous rows.
#define QK64_EPI(A00,A01,A10,A11,A20,A21,A30,A31, dst0, SC)                    \
  _Pragma("unroll")                                                            \
  for (int p = 0; p < 2; ++p) {                                                \
    if (wr == p) {                                                             \
      ROPEW64(0, 0, A00, SC) ROPEW64(0, 1, A01, SC)                            \
      ROPEW64(1, 0, A10, SC) ROPEW64(1, 1, A11, SC)                            \
      ROPEW64(2, 0, A20, SC) ROPEW64(2, 1, A21, SC)                            \
      ROPEW64(3, 0, A30, SC) ROPEW64(3, 1, A31, SC)                            \
    }                                                                          \
    __syncthreads();                                                           \
    const int s_r = tid >> 2, quad = tid & 3;                                  \
    const int grow = bm + p * 64 + s_r;                                        \
    const int b_ = grow >> 11, s_ = grow & (SEQ - 1);                          \
    bf16* dstp = (dst0) + ((size_t)(b_ * NH + h) * SEQ + s_) * DKH +           \
                 quad * 16;                                                    \
    _Pragma("unroll")                                                          \
    for (int j = 0; j < 2; ++j)                                                \
      *(float4*)(dstp + j * 8) =                                               \
          *(const float4*)((char*)LDSBUF + s_r * 272 + quad * 32 + j * 16);    \
    __syncthreads();                                                           \
  }

// ---- V path (R15-proven): C(128x128) = A@Wv^T -> Vd [B,H,dk,S] transposed.
#define AS_BASE(buf) ((char*)LDSBUF + (buf) * 8192)
#define BS_BASE(buf) ((char*)LDSBUF + 16384 + (buf) * 8192)

#define GEMM_STAGE(buf, kk)                                                    \
  gload_lds16(AS_BASE(buf) + (w * 64) * 16, asrc0 + (kk));                     \
  gload_lds16(BS_BASE(buf) + (w * 64) * 16, bsrc0 + (kk));                     \
  gload_lds16(AS_BASE(buf) + (w * 64 + 256) * 16, asrc1 + (kk));               \
  gload_lds16(BS_BASE(buf) + (w * 64 + 256) * 16, bsrc1 + (kk));

#define GEMM_MAINLOOP(Aptr, Bptr)                                              \
  const int c_0 = w * 64 + lane;                                               \
  const int row0_ = c_0 >> 2, seg0_ = (c_0 & 3) ^ ((row0_ >> 1) & 3);          \
  const int c_1 = c_0 + 256;                                                   \
  const int row1_ = c_1 >> 2, seg1_ = (c_1 & 3) ^ ((row1_ >> 1) & 3);          \
  const bf16* asrc0 = (Aptr) + (size_t)(bm + row0_) * D_MODEL + seg0_ * 8;     \
  const bf16* asrc1 = (Aptr) + (size_t)(bm + row1_) * D_MODEL + seg1_ * 8;     \
  const bf16* bsrc0 = (Bptr) + (size_t)(bn + row0_) * D_MODEL + seg0_ * 8;     \
  const bf16* bsrc1 = (Bptr) + (size_t)(bn + row1_) * D_MODEL + seg1_ * 8;     \
  const int gsw = (g ^ ((r >> 1) & 3)) * 8;                                    \
  GEMM_STAGE(0, 0)                                                             \
  __syncthreads();                                                             \
  int cub = 0;                                                                 \
  for (int kt = 0; kt < 32; ++kt) {                                            \
    if (kt + 1 < 32) { GEMM_STAGE(cub ^ 1, (kt + 1) * 32) }                    \
    const bf16* Abase = (const bf16*)AS_BASE(cub) + (wr * 64 + r) * 32 + gsw;  \
    const bf16* Bbase = (const bf16*)BS_BASE(cub) + (wc * 64 + r) * 32 + gsw;  \
    bf16x8 a0 = *(const bf16x8*)(Abase + 0 * 512);                             \
    bf16x8 a1 = *(const bf16x8*)(Abase + 1 * 512);                             \
    bf16x8 a2 = *(const bf16x8*)(Abase + 2 * 512);                             \
    bf16x8 a3 = *(const bf16x8*)(Abase + 3 * 512);                             \
    bf16x8 b0 = *(const bf16x8*)(Bbase + 0 * 512);                             \
    bf16x8 b1 = *(const bf16x8*)(Bbase + 1 * 512);                             \
    bf16x8 b2 = *(const bf16x8*)(Bbase + 2 * 512);                             \
    bf16x8 b3 = *(const bf16x8*)(Bbase + 3 * 512);                             \
    __builtin_amdgcn_s_setprio(1);                                             \
    c00 = mfma16(a0, b0, c00); c01 = mfma16(a0, b1, c01);                      \
    c02 = mfma16(a0, b2, c02); c03 = mfma16(a0, b3, c03);                      \
    c10 = mfma16(a1, b0, c10); c11 = mfma16(a1, b1, c11);                      \
    c12 = mfma16(a1, b2, c12); c13 = mfma16(a1, b3, c13);                      \
    c20 = mfma16(a2, b0, c20); c21 = mfma16(a2, b1, c21);                      \
    c22 = mfma16(a2, b2, c22); c23 = mfma16(a2, b3, c23);                      \
    c30 = mfma16(a3, b0, c30); c31 = mfma16(a3, b1, c31);                      \
    c32 = mfma16(a3, b2, c32); c33 = mfma16(a3, b3, c33);                      \
    __builtin_amdgcn_s_setprio(0);                                             \
    __syncthreads();                                                           \
    cub ^= 1;                                                                  \
  }

#define V_WRITE(mm, nn, CV)                                                    \
  _Pragma("unroll")                                                            \
  for (int reg = 0; reg < 4; ++reg) {                                          \
    const int crow = nn * 16 + r;                                              \
    const int s_l = wr * 64 + mm * 16 + g * 4 + reg;                           \
    *(bf16*)((char*)LDSBUF + crow * 272 + s_l * 2) = (bf16)CV[reg];            \
  }

// flat grid (16,96) = 1536 blocks. XCD-chunked l = (orig%8)*192 + orig/8.
// l%3<2 -> QK block id = (l/3)*2 + l%3 (of 1024); l%3==2 -> V block id = l/3.
__global__ __launch_bounds__(256, 2) void gemm_proj(
    const bf16* __restrict__ A,
    const bf16* __restrict__ Wq, const bf16* __restrict__ Wk,
    const bf16* __restrict__ Wv,
    bf16* __restrict__ Qd, bf16* __restrict__ Kd, bf16* __restrict__ Vd,
    const float2* __restrict__ ropetab) {
  __shared__ __align__(16) char LDSBUF[32768];
  const int orig = (int)(blockIdx.x + (blockIdx.y << 4));
  const int l = (orig & 7) * 192 + (orig >> 3);
  const int grp = l / 3, rem = l - grp * 3;
  const int tid = threadIdx.x, lane = tid & 63, w = tid >> 6;
  const int wr = w >> 1, wc = w & 1;
  const int r = lane & 15, g = lane >> 4;

  if (rem < 2) {
    // ---------- QK64 path ----------
    const int id = grp * 2 + rem;          // 0..1023
    const int bm = (id >> 4) * 128;
    const int h = id & 15;
    const int bn = h * 64;

    // staging sources (pre-swizzled k-segment; linear LDS dest)
    const int ar0 = tid >> 2, as0 = (tid & 3) ^ ((ar0 >> 1) & 3);
    const int cA1 = tid + 256;
    const int ar1 = cA1 >> 2, as1 = (cA1 & 3) ^ ((ar1 >> 1) & 3);
    const bf16* asrc0 = A + (size_t)(bm + ar0) * D_MODEL + as0 * 8;
    const bf16* asrc1 = A + (size_t)(bm + ar1) * D_MODEL + as1 * 8;
    const int br = tid >> 2, bs = (tid & 3) ^ ((br >> 1) & 3);
    const bf16* bqsrc = Wq + (size_t)(bn + br) * D_MODEL + bs * 8;
    const bf16* bksrc = Wk + (size_t)(bn + br) * D_MODEL + bs * 8;
    const int gsw = (g ^ ((r >> 1) & 3)) * 8;

    floatx4 q00 = {}, q01 = {}, q10 = {}, q11 = {};
    floatx4 q20 = {}, q21 = {}, q30 = {}, q31 = {};
    floatx4 k00 = {}, k01 = {}, k10 = {}, k11 = {};
    floatx4 k20 = {}, k21 = {}, k30 = {}, k31 = {};

    QK64_STAGE(0, 0)
    __syncthreads();
    int cub = 0;
    for (int kt = 0; kt < 32; ++kt) {
      if (kt + 1 < 32) { QK64_STAGE(cub ^ 1, (kt + 1) * 32) }
      const bf16* Abase = (const bf16*)QK64A(cub) + (wr * 64 + r) * 32 + gsw;
      const bf16* Qbase = (const bf16*)QK64Q(cub) + (wc * 32 + r) * 32 + gsw;
      const bf16* Kbase = (const bf16*)QK64K(cub) + (wc * 32 + r) * 32 + gsw;
      bf16x8 a0 = *(const bf16x8*)(Abase + 0 * 512);
      bf16x8 a1 = *(const bf16x8*)(Abase + 1 * 512);
      bf16x8 a2 = *(const bf16x8*)(Abase + 2 * 512);
      bf16x8 a3 = *(const bf16x8*)(Abase + 3 * 512);
      bf16x8 bq0 = *(const bf16x8*)(Qbase + 0 * 512);
      bf16x8 bq1 = *(const bf16x8*)(Qbase + 1 * 512);
      bf16x8 bk0 = *(const bf16x8*)(Kbase + 0 * 512);
      bf16x8 bk1 = *(const bf16x8*)(Kbase + 1 * 512);
      __builtin_amdgcn_s_setprio(1);
      q00 = mfma16(a0, bq0, q00); q01 = mfma16(a0, bq1, q01);
      k00 = mfma16(a0, bk0, k00); k01 = mfma16(a0, bk1, k01);
      q10 = mfma16(a1, bq0, q10); q11 = mfma16(a1, bq1, q11);
      k10 = mfma16(a1, bk0, k10); k11 = mfma16(a1, bk1, k11);
      q20 = mfma16(a2, bq0, q20); q21 = mfma16(a2, bq1, q21);
      k20 = mfma16(a2, bk0, k20); k21 = mfma16(a2, bk1, k21);
      q30 = mfma16(a3, bq0, q30); q31 = mfma16(a3, bq1, q31);
      k30 = mfma16(a3, bk0, k30); k31 = mfma16(a3, bk1, k31);
      __builtin_amdgcn_s_setprio(0);
      __syncthreads();
      cub ^= 1;
    }

    QK64_EPI(q00, q01, q10, q11, q20, q21, q30, q31, Qd, 0.125f)
    QK64_EPI(k00, k01, k10, k11, k20, k21, k30, k31, Kd, 1.0f)
  } else {
    // ---------- V path (unchanged structure) ----------
    const int id = grp;                    // 0..511
    const int bm = (id >> 3) * 128, bn = (id & 7) * 128;
    const int hbase = bn >> 6;
    floatx4 c00 = {}, c01 = {}, c02 = {}, c03 = {};
    floatx4 c10 = {}, c11 = {}, c12 = {}, c13 = {};
    floatx4 c20 = {}, c21 = {}, c22 = {}, c23 = {};
    floatx4 c30 = {}, c31 = {}, c32 = {}, c33 = {};
    GEMM_MAINLOOP(A, Wv)

    const int b_ = bm >> 11, sbase = bm & (SEQ - 1);
#pragma unroll
    for (int p = 0; p < 2; ++p) {
      if (wc == p) {
        V_WRITE(0, 0, c00) V_WRITE(0, 1, c01) V_WRITE(0, 2, c02) V_WRITE(0, 3, c03)
        V_WRITE(1, 0, c10) V_WRITE(1, 1, c11) V_WRITE(1, 2, c12) V_WRITE(1, 3, c13)
        V_WRITE(2, 0, c20) V_WRITE(2, 1, c21) V_WRITE(2, 2, c22) V_WRITE(2, 3, c23)
        V_WRITE(3, 0, c30) V_WRITE(3, 1, c31) V_WRITE(3, 2, c32) V_WRITE(3, 3, c33)
      }
      __syncthreads();
      const int c_r = tid >> 2, quad = tid & 3;
      const int c = p * 64 + c_r;
      const int h_ = hbase + (c >> 6), d_ = c & 63;
      bf16* dstp = Vd + ((size_t)(b_ * NH + h_) * DKH + d_) * SEQ + sbase + quad * 32;
#pragma unroll
      for (int j = 0; j < 4; ++j)
        *(float4*)(dstp + j * 8) =
            *(const float4*)((char*)LDSBUF + c_r * 272 + quad * 64 + j * 16);
      __syncthreads();
    }
  }
}

// ---------------- output projection: d_out = AO @ Wo^T (fp32 row-major) ----------------
#define OUT_EPI(mm, nn, CV)                                                    \
  _Pragma("unroll")                                                            \
  for (int reg = 0; reg < 4; ++reg) {                                          \
    const int grow = bm + wr * 64 + mm * 16 + g * 4 + reg;                     \
    const int gcol = bn + wc * 64 + nn * 16 + r;                               \
    C[(size_t)grow * D_MODEL + gcol] = CV[reg];                                \
  }

__global__ __launch_bounds__(256, 3) void gemm_out(const bf16* __restrict__ A,
                                                   const bf16* __restrict__ Bw,
                                                   float* __restrict__ C) {
  __shared__ __align__(16) char LDSBUF[32768];
  const int orig = (int)(blockIdx.x + (blockIdx.y << 3));
  const int l = (orig & 7) * 64 + (orig >> 3);
  const int bm = (l >> 3) * 128, bn = (l & 7) * 128;
  const int tid = threadIdx.x, lane = tid & 63, w = tid >> 6;
  const int wr = w >> 1, wc = w & 1;
  const int r = lane & 15, g = lane >> 4;
  floatx4 c00 = {}, c01 = {}, c02 = {}, c03 = {};
  floatx4 c10 = {}, c11 = {}, c12 = {}, c13 = {};
  floatx4 c20 = {}, c21 = {}, c22 = {}, c23 = {};
  floatx4 c30 = {}, c31 = {}, c32 = {}, c33 = {};
  GEMM_MAINLOOP(A, Bw)
  OUT_EPI(0, 0, c00) OUT_EPI(0, 1, c01) OUT_EPI(0, 2, c02) OUT_EPI(0, 3, c03)
  OUT_EPI(1, 0, c10) OUT_EPI(1, 1, c11) OUT_EPI(1, 2, c12) OUT_EPI(1, 3, c13)
  OUT_EPI(2, 0, c20) OUT_EPI(2, 1, c21) OUT_EPI(2, 2, c22) OUT_EPI(2, 3, c23)
  OUT_EPI(3, 0, c30) OUT_EPI(3, 1, c31) OUT_EPI(3, 2, c32) OUT_EPI(3, 3, c33)
}

// ---------------- causal flash attention (R19/R21-proven, unchanged) ----------------
__global__ __launch_bounds__(256, 3) void attn128(const bf16* __restrict__ Q,
                                                  const bf16* __restrict__ Kk,
                                                  const bf16* __restrict__ Vt,
                                                  bf16* __restrict__ AO) {
  const int orig = (int)(blockIdx.x + (blockIdx.y << 4));
  const int i_ = orig >> 3;
  const int qt = 15 - (i_ >> 3);
  const int bh = (orig & 7) * 8 + (i_ & 7);
  const int b = bh >> 4, h = bh & 15;
  const int tid = threadIdx.x, lane = tid & 63, w = tid >> 6;
  const int r = lane & 15, g = lane >> 4;
  const int q0 = qt * 128 + w * 32;

  const bf16* Qb = Q + (size_t)bh * SEQ * DKH;
  const bf16* Kb = Kk + (size_t)bh * SEQ * DKH;
  const bf16* Vb = Vt + (size_t)bh * DKH * SEQ;

  __shared__ bf16 Ks[2][64 * 64];  // [token][d], XOR-swizzled
  __shared__ bf16 Vs[2][64 * 64];  // [d][token], XOR-swizzled
  __shared__ bf16 Ps[4][32 * 64];  // per-wave P, [q-row][token], XOR-swizzled

  int ldsoff[2];
  const char* ksrc[2];
  const char* vsrc[2];
#pragma unroll
  for (int j = 0; j < 2; ++j) {
    const int L = (w * 64 + lane + 256 * j) * 16;
    const int S = L ^ (((L >> 7) & 7) << 4);
    ldsoff[j] = (w * 64 + 256 * j) * 16;
    ksrc[j] = (const char*)Kb + S;
    vsrc[j] = (const char*)Vb + (size_t)(S >> 7) * (SEQ * 2) + (S & 127);
  }

#define ATTN_STAGE(buf, tt)                                                   \
  _Pragma("unroll")                                                           \
  for (int j = 0; j < 2; ++j) {                                               \
    gload_lds16((char*)Ks[buf] + ldsoff[j], ksrc[j] + (size_t)(tt) * 8192);   \
    gload_lds16((char*)Vs[buf] + ldsoff[j], vsrc[j] + (size_t)(tt) * 128);    \
  }

#define SM_TILE(MASKED)                                                        \
  _Pragma("unroll")                                                            \
  for (int m = 0; m < 2; ++m) {                                                \
    const int qq_ = q0 + m * 16 + r;                                           \
    const int wl_ = m * 16 + r;                                                \
    _Pragma("unroll")                                                          \
    for (int nf = 0; nf < 4; ++nf) {                                           \
      floatx4 p;                                                               \
      _Pragma("unroll")                                                        \
      for (int reg = 0; reg < 4; ++reg) {                                      \
        float pe = exp2f(fmaf(sc[m][nf][reg], 1.442695041f, -17.31234049f));   \
        if (MASKED && (t0 + nf * 16 + g * 4 + reg > qq_)) pe = 0.f;            \
        p[reg] = pe;                                                           \
      }                                                                        \
      l2[m] += p;                                                              \
      unsigned u0, u1;                                                         \
      asm("v_cvt_pk_bf16_f32 %0, %1, %2" : "=v"(u0) : "v"(p[0]), "v"(p[1]));   \
      asm("v_cvt_pk_bf16_f32 %0, %1, %2" : "=v"(u1) : "v"(p[2]), "v"(p[3]));   \
      const int pb = (wl_ * 128 + nf * 32 + g * 8) ^ ((wl_ & 7) << 4);         \
      *(uint2*)((char*)Ps[w] + pb) = make_uint2(u0, u1);                       \
    }                                                                          \
  }

  bf16x8 qf[2][2];
#pragma unroll
  for (int m = 0; m < 2; ++m)
#pragma unroll
    for (int ks = 0; ks < 2; ++ks)
      qf[m][ks] = *(const bf16x8*)(Qb + (size_t)(q0 + m * 16 + r) * DKH + ks * 32 + g * 8);

  floatx4 o[2][4] = {};
  floatx4 l2[2] = {};

  const int nt = 2 * qt + 2;
  ATTN_STAGE(0, 0)
  __syncthreads();
  int cu = 0;
  for (int t = 0; t < nt; ++t) {
    if (t + 1 < nt) ATTN_STAGE(cu ^ 1, t + 1)
    const int t0 = t * 64;

    floatx4 sc[2][4];
    __builtin_amdgcn_s_setprio(1);
#pragma unroll
    for (int nf = 0; nf < 4; ++nf) {
      const int row = nf * 16 + r;
      const int off0 = (row * 128 + g * 16) ^ ((row & 7) << 4);
      bf16x8 kf0 = *(const bf16x8*)((const char*)Ks[cu] + off0);
      bf16x8 kf1 = *(const bf16x8*)((const char*)Ks[cu] + (off0 ^ 64));
      sc[0][nf] = mfma16(kf1, qf[0][1], mfma16(kf0, qf[0][0], floatx4{0.f, 0.f, 0.f, 0.f}));
      sc[1][nf] = mfma16(kf1, qf[1][1], mfma16(kf0, qf[1][0], floatx4{0.f, 0.f, 0.f, 0.f}));
    }
    __builtin_amdgcn_s_setprio(0);

    const bool edge = (t0 + 63 > q0);
    if (edge) {
      SM_TILE(1)
    } else {
      SM_TILE(0)
    }
    asm volatile("s_waitcnt lgkmcnt(0)" ::: "memory");

    bf16x8 pf[2][2];
#pragma unroll
    for (int m = 0; m < 2; ++m)
#pragma unroll
      for (int ks = 0; ks < 2; ++ks) {
        const int prow = m * 16 + r;
        const int ab = (prow * 128 + ks * 64 + g * 16) ^ ((prow & 7) << 4);
        pf[m][ks] = *(const bf16x8*)((const char*)Ps[w] + ab);
      }
    __builtin_amdgcn_s_setprio(1);
#pragma unroll
    for (int nf = 0; nf < 4; ++nf) {
      const int vrow = nf * 16 + r;
      const int vb0 = (vrow * 128 + g * 16) ^ ((vrow & 7) << 4);
      bf16x8 vf0 = *(const bf16x8*)((const char*)Vs[cu] + vb0);
      bf16x8 vf1 = *(const bf16x8*)((const char*)Vs[cu] + (vb0 ^ 64));
#pragma unroll
      for (int m = 0; m < 2; ++m)
        o[m][nf] = mfma16(pf[m][1], vf1, mfma16(pf[m][0], vf0, o[m][nf]));
    }
    __builtin_amdgcn_s_setprio(0);
    __syncthreads();
    cu ^= 1;
  }

  float lsm[2];
#pragma unroll
  for (int m = 0; m < 2; ++m) {
    float ls = l2[m][0] + l2[m][1] + l2[m][2] + l2[m][3];
    ls += __shfl_xor(ls, 16);
    ls += __shfl_xor(ls, 32);
    lsm[m] = ls;
  }
  float linv[2][4];
#pragma unroll
  for (int m = 0; m < 2; ++m)
#pragma unroll
    for (int reg = 0; reg < 4; ++reg)
      linv[m][reg] = 1.f / __shfl(lsm[m], g * 4 + reg);

#pragma unroll
  for (int m = 0; m < 2; ++m)
#pragma unroll
    for (int nf = 0; nf < 4; ++nf)
#pragma unroll
      for (int reg = 0; reg < 4; ++reg) {
        const int s = q0 + m * 16 + g * 4 + reg;
        const int d = nf * 16 + r;
        const float val = o[m][nf][reg] * linv[m][reg];
        AO[((size_t)(b * SEQ + s)) * D_MODEL + h * DKH + d] = (bf16)val;
      }
}

// ---------------- launcher ----------------
extern "C" void kernel_launch(void* const* d_in, const int* in_sizes, int n_in,
                              void* d_out, int out_size, void* d_ws, size_t ws_size,
                              hipStream_t stream) {
  const float* x = (const float*)d_in[0];
  const int* tokpos = (const int*)d_in[1];
  const float* Wq = (const float*)d_in[2];
  const float* Wk = (const float*)d_in[3];
  const float* Wv = (const float*)d_in[4];
  const float* Wo = (const float*)d_in[5];
  float* out = (float*)d_out;

  char* ws = (char*)d_ws;
  if (ws_size < (72ull << 20)) return;  // need 72 MiB scratch

  bf16* xb  = (bf16*)(ws);                     // 16 MiB [8192,1024]
  bf16* wb0 = (bf16*)(ws + (16ull << 20));     // 2 MiB each
  bf16* wb1 = (bf16*)(ws + (18ull << 20));
  bf16* wb2 = (bf16*)(ws + (20ull << 20));
  bf16* wb3 = (bf16*)(ws + (22ull << 20));
  bf16* Qb  = (bf16*)(ws + (24ull << 20));     // 16 MiB [B,H,S,64]
  bf16* Kb  = (bf16*)(ws + (40ull << 20));     // 16 MiB
  bf16* Vt  = (bf16*)(ws + (56ull << 20));     // 16 MiB [B,H,64,S]
  bf16* AO  = (bf16*)(ws);                     // reuse xb region (dead after QKV)
  // RoPE table lives in d_out's head (512 KB); fully overwritten by gemm_out later.
  float2* ropetab = (float2*)d_out;

  cvt_all<<<12544, 256, 0, stream>>>((const float4*)x, (const float4*)Wq,
                                     (const float4*)Wk, (const float4*)Wv,
                                     (const float4*)Wo, (bf16x4*)xb,
                                     (bf16x4*)wb0, (bf16x4*)wb1,
                                     (bf16x4*)wb2, (bf16x4*)wb3,
                                     tokpos, ropetab);

  gemm_proj<<<dim3(16, 96), 256, 0, stream>>>(xb, wb0, wb1, wb2,
                                              Qb, Kb, Vt, ropetab);
  attn128<<<dim3(16, 64), 256, 0, stream>>>(Qb, Kb, Vt, AO);
  gemm_out<<<dim3(8, 64), 256, 0, stream>>>(AO, wb3, out);
}

// Round 25
// 171.027 us; speedup vs baseline: 1.0981x; 1.0981x over previous
//
#include <hip/hip_runtime.h>

typedef __bf16 bf16;
typedef bf16 bf16x8 __attribute__((ext_vector_type(8)));
typedef bf16 bf16x4 __attribute__((ext_vector_type(4)));
typedef float floatx4 __attribute__((ext_vector_type(4)));

#define D_MODEL 1024
#define SEQ     2048
#define NB      4
#define NH      16
#define DKH     64
// log2(10000)/32
#define ROPE_L2 0.4152410118609203f

__device__ __forceinline__ floatx4 mfma16(bf16x8 a, bf16x8 b, floatx4 c) {
  return __builtin_amdgcn_mfma_f32_16x16x32_bf16(a, b, c, 0, 0, 0);
}

// Async global->LDS, 16B per lane. lds base must be wave-uniform; HW adds lane*16.
__device__ __forceinline__ void gload_lds16(void* lds_uniform, const void* gsrc) {
  __builtin_amdgcn_global_load_lds(
      (__attribute__((address_space(1))) unsigned int*)(void*)(gsrc),
      (__attribute__((address_space(3))) unsigned int*)lds_uniform,
      16, 0, 0);
}

// ------- fused prep: fp32->bf16 (x + 4 weights) AND RoPE table, ONE launch -------
__global__ __launch_bounds__(256) void cvt_all(
    const float4* __restrict__ x,
    const float4* __restrict__ wq, const float4* __restrict__ wk,
    const float4* __restrict__ wv, const float4* __restrict__ wo,
    bf16x4* __restrict__ xb,
    bf16x4* __restrict__ b0, bf16x4* __restrict__ b1,
    bf16x4* __restrict__ b2, bf16x4* __restrict__ b3,
    const int* __restrict__ tokpos, float2* __restrict__ ropetab) {
  const int i = blockIdx.x * 256 + threadIdx.x;
  if (i < (1 << 21) + (1 << 20)) {
    const float4* src;
    bf16x4* dst;
    int off;
    if (i < (1 << 21)) {
      src = x; dst = xb; off = i;
    } else {
      const int j = i - (1 << 21);
      const int widx = j >> 18;
      off = j & ((1 << 18) - 1);
      src = (widx == 0) ? wq : (widx == 1) ? wk : (widx == 2) ? wv : wo;
      dst = (widx == 0) ? b0 : (widx == 1) ? b1 : (widx == 2) ? b2 : b3;
    }
    const float4 v = src[off];
    bf16x4 o;
    o[0] = (bf16)v.x; o[1] = (bf16)v.y; o[2] = (bf16)v.z; o[3] = (bf16)v.w;
    dst[off] = o;
  } else {
    const int k = i - (1 << 21) - (1 << 20);  // [0, 65536)
    const int s = k >> 5, i2 = k & 31;
    const float ang = (float)tokpos[s] * exp2f(-(float)i2 * ROPE_L2);
    float sn, cs;
    sincosf(ang, &sn, &cs);
    ropetab[k] = make_float2(sn, cs);
  }
}

// =============== merged projection kernel: z=0 QK-fused, z=1 V ===============
#define QK_SRC_DECL(Aptr, Bq, Bk)                                              \
  const int c_0 = w * 64 + lane;                                               \
  const int row0_ = c_0 >> 2, seg0_ = (c_0 & 3) ^ ((row0_ >> 1) & 3);          \
  const int c_1 = c_0 + 256;                                                   \
  const int row1_ = c_1 >> 2, seg1_ = (c_1 & 3) ^ ((row1_ >> 1) & 3);          \
  const bf16* asrc0 = (Aptr) + (size_t)(bm + row0_) * D_MODEL + seg0_ * 8;     \
  const bf16* asrc1 = (Aptr) + (size_t)(bm + row1_) * D_MODEL + seg1_ * 8;     \
  const bf16* bqsrc0 = (Bq) + (size_t)(bn + row0_) * D_MODEL + seg0_ * 8;      \
  const bf16* bqsrc1 = (Bq) + (size_t)(bn + row1_) * D_MODEL + seg1_ * 8;      \
  const bf16* bksrc0 = (Bk) + (size_t)(bn + row0_) * D_MODEL + seg0_ * 8;      \
  const bf16* bksrc1 = (Bk) + (size_t)(bn + row1_) * D_MODEL + seg1_ * 8;     \
  const int gsw = (g ^ ((r >> 1) & 3)) * 8;

#define QKA(buf) ((char*)LDSBUF + (buf) * 8192)
#define QKQ(buf) ((char*)LDSBUF + 16384 + (buf) * 8192)
#define QKK(buf) ((char*)LDSBUF + 32768 + (buf) * 8192)

#define QK_STAGE(buf, kk)                                                      \
  gload_lds16(QKA(buf) + (w * 64) * 16, asrc0 + (kk));                         \
  gload_lds16(QKQ(buf) + (w * 64) * 16, bqsrc0 + (kk));                        \
  gload_lds16(QKK(buf) + (w * 64) * 16, bksrc0 + (kk));                        \
  gload_lds16(QKA(buf) + (w * 64 + 256) * 16, asrc1 + (kk));                   \
  gload_lds16(QKQ(buf) + (w * 64 + 256) * 16, bqsrc1 + (kk));                  \
  gload_lds16(QKK(buf) + (w * 64 + 256) * 16, bksrc1 + (kk));

#define ROPEW(mm, nn, CV, SC)                                                  \
  _Pragma("unroll")                                                            \
  for (int reg = 0; reg < 4; ++reg) {                                          \
    const int srow = mm * 16 + g * 4 + reg;                                    \
    const int c = wc * 64 + nn * 16 + r;                                       \
    const int s_ = (bm + wr * 64 + srow) & (SEQ - 1);                          \
    const int d_ = c & 63;                                                     \
    float v = CV[reg];                                                         \
    float pp = __shfl_xor(v, 1);                                               \
    const float2 sc2 = ropetab[s_ * 32 + (d_ >> 1)];                           \
    float res = ((d_ & 1) == 0) ? (sc2.y * v - sc2.x * pp)                     \
                                : (sc2.x * pp + sc2.y * v);                    \
    res *= SC;                                                                 \
    *(bf16*)((char*)LDSBUF + srow * 272 + c * 2) = (bf16)res;                  \
  }

#define QK_EPI(A00,A01,A02,A03,A10,A11,A12,A13,A20,A21,A22,A23,A30,A31,A32,A33,\
               dst0, SC)                                                       \
  _Pragma("unroll")                                                            \
  for (int p = 0; p < 2; ++p) {                                                \
    if (wr == p) {                                                             \
      ROPEW(0, 0, A00, SC) ROPEW(0, 1, A01, SC) ROPEW(0, 2, A02, SC)           \
      ROPEW(0, 3, A03, SC) ROPEW(1, 0, A10, SC) ROPEW(1, 1, A11, SC)           \
      ROPEW(1, 2, A12, SC) ROPEW(1, 3, A13, SC) ROPEW(2, 0, A20, SC)           \
      ROPEW(2, 1, A21, SC) ROPEW(2, 2, A22, SC) ROPEW(2, 3, A23, SC)           \
      ROPEW(3, 0, A30, SC) ROPEW(3, 1, A31, SC) ROPEW(3, 2, A32, SC)           \
      ROPEW(3, 3, A33, SC)                                                     \
    }                                                                          \
    __syncthreads();                                                           \
    const int s_r = tid >> 2, quad = tid & 3;                                  \
    const int grow = bm + p * 64 + s_r;                                        \
    const int b_ = grow >> 11, s_ = grow & (SEQ - 1);                          \
    const int h_ = hbase + (quad >> 1);                                        \
    bf16* dstp = (dst0) + ((size_t)(b_ * NH + h_) * SEQ + s_) * DKH +          \
                 (quad & 1) * 32;                                              \
    _Pragma("unroll")                                                          \
    for (int j = 0; j < 4; ++j)                                                \
      *(float4*)(dstp + j * 8) =                                               \
          *(const float4*)((char*)LDSBUF + s_r * 272 + quad * 64 + j * 16);    \
    __syncthreads();                                                           \
  }

// V-path LDS (first 32KB of the arena)
#define AS_BASE(buf) ((char*)LDSBUF + (buf) * 8192)
#define BS_BASE(buf) ((char*)LDSBUF + 16384 + (buf) * 8192)

#define GEMM_STAGE(buf, kk)                                                    \
  gload_lds16(AS_BASE(buf) + (w * 64) * 16, asrc0 + (kk));                     \
  gload_lds16(BS_BASE(buf) + (w * 64) * 16, bsrc0 + (kk));                     \
  gload_lds16(AS_BASE(buf) + (w * 64 + 256) * 16, asrc1 + (kk));               \
  gload_lds16(BS_BASE(buf) + (w * 64 + 256) * 16, bsrc1 + (kk));

#define GEMM_MAINLOOP(Aptr, Bptr)                                              \
  const int c_0 = w * 64 + lane;                                               \
  const int row0_ = c_0 >> 2, seg0_ = (c_0 & 3) ^ ((row0_ >> 1) & 3);          \
  const int c_1 = c_0 + 256;                                                   \
  const int row1_ = c_1 >> 2, seg1_ = (c_1 & 3) ^ ((row1_ >> 1) & 3);          \
  const bf16* asrc0 = (Aptr) + (size_t)(bm + row0_) * D_MODEL + seg0_ * 8;     \
  const bf16* asrc1 = (Aptr) + (size_t)(bm + row1_) * D_MODEL + seg1_ * 8;     \
  const bf16* bsrc0 = (Bptr) + (size_t)(bn + row0_) * D_MODEL + seg0_ * 8;     \
  const bf16* bsrc1 = (Bptr) + (size_t)(bn + row1_) * D_MODEL + seg1_ * 8;     \
  const int gsw = (g ^ ((r >> 1) & 3)) * 8;                                    \
  GEMM_STAGE(0, 0)                                                             \
  __syncthreads();                                                             \
  int cub = 0;                                                                 \
  for (int kt = 0; kt < 32; ++kt) {                                            \
    if (kt + 1 < 32) { GEMM_STAGE(cub ^ 1, (kt + 1) * 32) }                    \
    const bf16* Abase = (const bf16*)AS_BASE(cub) + (wr * 64 + r) * 32 + gsw;  \
    const bf16* Bbase = (const bf16*)BS_BASE(cub) + (wc * 64 + r) * 32 + gsw;  \
    bf16x8 a0 = *(const bf16x8*)(Abase + 0 * 512);                             \
    bf16x8 a1 = *(const bf16x8*)(Abase + 1 * 512);                             \
    bf16x8 a2 = *(const bf16x8*)(Abase + 2 * 512);                             \
    bf16x8 a3 = *(const bf16x8*)(Abase + 3 * 512);                             \
    bf16x8 b0 = *(const bf16x8*)(Bbase + 0 * 512);                             \
    bf16x8 b1 = *(const bf16x8*)(Bbase + 1 * 512);                             \
    bf16x8 b2 = *(const bf16x8*)(Bbase + 2 * 512);                             \
    bf16x8 b3 = *(const bf16x8*)(Bbase + 3 * 512);                             \
    __builtin_amdgcn_s_setprio(1);                                             \
    c00 = mfma16(a0, b0, c00); c01 = mfma16(a0, b1, c01);                      \
    c02 = mfma16(a0, b2, c02); c03 = mfma16(a0, b3, c03);                      \
    c10 = mfma16(a1, b0, c10); c11 = mfma16(a1, b1, c11);                      \
    c12 = mfma16(a1, b2, c12); c13 = mfma16(a1, b3, c13);                      \
    c20 = mfma16(a2, b0, c20); c21 = mfma16(a2, b1, c21);                      \
    c22 = mfma16(a2, b2, c22); c23 = mfma16(a2, b3, c23);                      \
    c30 = mfma16(a3, b0, c30); c31 = mfma16(a3, b1, c31);                      \
    c32 = mfma16(a3, b2, c32); c33 = mfma16(a3, b3, c33);                      \
    __builtin_amdgcn_s_setprio(0);                                             \
    __syncthreads();                                                           \
    cub ^= 1;                                                                  \
  }

#define V_WRITE(mm, nn, CV)                                                    \
  _Pragma("unroll")                                                            \
  for (int reg = 0; reg < 4; ++reg) {                                          \
    const int crow = nn * 16 + r;                                              \
    const int s_l = wr * 64 + mm * 16 + g * 4 + reg;                           \
    *(bf16*)((char*)LDSBUF + crow * 272 + s_l * 2) = (bf16)CV[reg];            \
  }

// grid (8,64,2). z=0: Q&K (RoPE, bounce-store). z=1: V -> [B,H,dk,S].
__global__ __launch_bounds__(256, 2) void gemm_proj(
    const bf16* __restrict__ A,
    const bf16* __restrict__ Wq, const bf16* __restrict__ Wk,
    const bf16* __restrict__ Wv,
    bf16* __restrict__ Qd, bf16* __restrict__ Kd, bf16* __restrict__ Vd,
    const float2* __restrict__ ropetab) {
  __shared__ __align__(16) char LDSBUF[49152];
  const int orig = (int)(blockIdx.x + (blockIdx.y << 3));
  const int l = (orig & 7) * 64 + (orig >> 3);
  const int bm = (l >> 3) * 128, bn = (l & 7) * 128;
  const int tid = threadIdx.x, lane = tid & 63, w = tid >> 6;
  const int wr = w >> 1, wc = w & 1;
  const int r = lane & 15, g = lane >> 4;
  const int hbase = bn >> 6;

  if (blockIdx.z == 0) {
    floatx4 q00 = {}, q01 = {}, q02 = {}, q03 = {};
    floatx4 q10 = {}, q11 = {}, q12 = {}, q13 = {};
    floatx4 q20 = {}, q21 = {}, q22 = {}, q23 = {};
    floatx4 q30 = {}, q31 = {}, q32 = {}, q33 = {};
    floatx4 k00 = {}, k01 = {}, k02 = {}, k03 = {};
    floatx4 k10 = {}, k11 = {}, k12 = {}, k13 = {};
    floatx4 k20 = {}, k21 = {}, k22 = {}, k23 = {};
    floatx4 k30 = {}, k31 = {}, k32 = {}, k33 = {};

    QK_SRC_DECL(A, Wq, Wk)
    QK_STAGE(0, 0)
    __syncthreads();
    int cub = 0;
    for (int kt = 0; kt < 32; ++kt) {
      if (kt + 1 < 32) { QK_STAGE(cub ^ 1, (kt + 1) * 32) }
      const bf16* Abase = (const bf16*)QKA(cub) + (wr * 64 + r) * 32 + gsw;
      const bf16* Qbase = (const bf16*)QKQ(cub) + (wc * 64 + r) * 32 + gsw;
      const bf16* Kbase = (const bf16*)QKK(cub) + (wc * 64 + r) * 32 + gsw;
      bf16x8 a0 = *(const bf16x8*)(Abase + 0 * 512);
      bf16x8 a1 = *(const bf16x8*)(Abase + 1 * 512);
      bf16x8 a2 = *(const bf16x8*)(Abase + 2 * 512);
      bf16x8 a3 = *(const bf16x8*)(Abase + 3 * 512);
      bf16x8 bq0 = *(const bf16x8*)(Qbase + 0 * 512);
      bf16x8 bq1 = *(const bf16x8*)(Qbase + 1 * 512);
      bf16x8 bq2 = *(const bf16x8*)(Qbase + 2 * 512);
      bf16x8 bq3 = *(const bf16x8*)(Qbase + 3 * 512);
      bf16x8 bk0 = *(const bf16x8*)(Kbase + 0 * 512);
      bf16x8 bk1 = *(const bf16x8*)(Kbase + 1 * 512);
      bf16x8 bk2 = *(const bf16x8*)(Kbase + 2 * 512);
      bf16x8 bk3 = *(const bf16x8*)(Kbase + 3 * 512);
      __builtin_amdgcn_s_setprio(1);
      q00 = mfma16(a0, bq0, q00); q01 = mfma16(a0, bq1, q01);
      q02 = mfma16(a0, bq2, q02); q03 = mfma16(a0, bq3, q03);
      k00 = mfma16(a0, bk0, k00); k01 = mfma16(a0, bk1, k01);
      k02 = mfma16(a0, bk2, k02); k03 = mfma16(a0, bk3, k03);
      q10 = mfma16(a1, bq0, q10); q11 = mfma16(a1, bq1, q11);
      q12 = mfma16(a1, bq2, q12); q13 = mfma16(a1, bq3, q13);
      k10 = mfma16(a1, bk0, k10); k11 = mfma16(a1, bk1, k11);
      k12 = mfma16(a1, bk2, k12); k13 = mfma16(a1, bk3, k13);
      q20 = mfma16(a2, bq0, q20); q21 = mfma16(a2, bq1, q21);
      q22 = mfma16(a2, bq2, q22); q23 = mfma16(a2, bq3, q23);
      k20 = mfma16(a2, bk0, k20); k21 = mfma16(a2, bk1, k21);
      k22 = mfma16(a2, bk2, k22); k23 = mfma16(a2, bk3, k23);
      q30 = mfma16(a3, bq0, q30); q31 = mfma16(a3, bq1, q31);
      q32 = mfma16(a3, bq2, q32); q33 = mfma16(a3, bq3, q33);
      k30 = mfma16(a3, bk0, k30); k31 = mfma16(a3, bk1, k31);
      k32 = mfma16(a3, bk2, k32); k33 = mfma16(a3, bk3, k33);
      __builtin_amdgcn_s_setprio(0);
      __syncthreads();
      cub ^= 1;
    }

    QK_EPI(q00,q01,q02,q03,q10,q11,q12,q13,q20,q21,q22,q23,q30,q31,q32,q33,
           Qd, 0.125f)
    QK_EPI(k00,k01,k02,k03,k10,k11,k12,k13,k20,k21,k22,k23,k30,k31,k32,k33,
           Kd, 1.0f)
  } else {
    floatx4 c00 = {}, c01 = {}, c02 = {}, c03 = {};
    floatx4 c10 = {}, c11 = {}, c12 = {}, c13 = {};
    floatx4 c20 = {}, c21 = {}, c22 = {}, c23 = {};
    floatx4 c30 = {}, c31 = {}, c32 = {}, c33 = {};
    GEMM_MAINLOOP(A, Wv)

    const int b_ = bm >> 11, sbase = bm & (SEQ - 1);
#pragma unroll
    for (int p = 0; p < 2; ++p) {
      if (wc == p) {
        V_WRITE(0, 0, c00) V_WRITE(0, 1, c01) V_WRITE(0, 2, c02) V_WRITE(0, 3, c03)
        V_WRITE(1, 0, c10) V_WRITE(1, 1, c11) V_WRITE(1, 2, c12) V_WRITE(1, 3, c13)
        V_WRITE(2, 0, c20) V_WRITE(2, 1, c21) V_WRITE(2, 2, c22) V_WRITE(2, 3, c23)
        V_WRITE(3, 0, c30) V_WRITE(3, 1, c31) V_WRITE(3, 2, c32) V_WRITE(3, 3, c33)
      }
      __syncthreads();
      const int c_r = tid >> 2, quad = tid & 3;
      const int c = p * 64 + c_r;
      const int h_ = hbase + (c >> 6), d_ = c & 63;
      bf16* dstp = Vd + ((size_t)(b_ * NH + h_) * DKH + d_) * SEQ + sbase + quad * 32;
#pragma unroll
      for (int j = 0; j < 4; ++j)
        *(float4*)(dstp + j * 8) =
            *(const float4*)((char*)LDSBUF + c_r * 272 + quad * 64 + j * 16);
      __syncthreads();
    }
  }
}

// ---------------- output projection: d_out = AO @ Wo^T (fp32 row-major) ----------------
#define OUT_EPI(mm, nn, CV)                                                    \
  _Pragma("unroll")                                                            \
  for (int reg = 0; reg < 4; ++reg) {                                          \
    const int grow = bm + wr * 64 + mm * 16 + g * 4 + reg;                     \
    const int gcol = bn + wc * 64 + nn * 16 + r;                               \
    C[(size_t)grow * D_MODEL + gcol] = CV[reg];                                \
  }

__global__ __launch_bounds__(256, 3) void gemm_out(const bf16* __restrict__ A,
                                                   const bf16* __restrict__ Bw,
                                                   float* __restrict__ C) {
  __shared__ __align__(16) char LDSBUF[32768];
  const int orig = (int)(blockIdx.x + (blockIdx.y << 3));
  const int l = (orig & 7) * 64 + (orig >> 3);
  const int bm = (l >> 3) * 128, bn = (l & 7) * 128;
  const int tid = threadIdx.x, lane = tid & 63, w = tid >> 6;
  const int wr = w >> 1, wc = w & 1;
  const int r = lane & 15, g = lane >> 4;
  floatx4 c00 = {}, c01 = {}, c02 = {}, c03 = {};
  floatx4 c10 = {}, c11 = {}, c12 = {}, c13 = {};
  floatx4 c20 = {}, c21 = {}, c22 = {}, c23 = {};
  floatx4 c30 = {}, c31 = {}, c32 = {}, c33 = {};
  GEMM_MAINLOOP(A, Bw)
  OUT_EPI(0, 0, c00) OUT_EPI(0, 1, c01) OUT_EPI(0, 2, c02) OUT_EPI(0, 3, c03)
  OUT_EPI(1, 0, c10) OUT_EPI(1, 1, c11) OUT_EPI(1, 2, c12) OUT_EPI(1, 3, c13)
  OUT_EPI(2, 0, c20) OUT_EPI(2, 1, c21) OUT_EPI(2, 2, c22) OUT_EPI(2, 3, c23)
  OUT_EPI(3, 0, c30) OUT_EPI(3, 1, c31) OUT_EPI(3, 2, c32) OUT_EPI(3, 3, c33)
}

// ---------------- causal flash attention (R19/R21-proven) ----------------
__global__ __launch_bounds__(256, 3) void attn128(const bf16* __restrict__ Q,
                                                  const bf16* __restrict__ Kk,
                                                  const bf16* __restrict__ Vt,
                                                  bf16* __restrict__ AO) {
  const int orig = (int)(blockIdx.x + (blockIdx.y << 4));
  const int i_ = orig >> 3;
  const int qt = 15 - (i_ >> 3);
  const int bh = (orig & 7) * 8 + (i_ & 7);
  const int b = bh >> 4, h = bh & 15;
  const int tid = threadIdx.x, lane = tid & 63, w = tid >> 6;
  const int r = lane & 15, g = lane >> 4;
  const int q0 = qt * 128 + w * 32;

  const bf16* Qb = Q + (size_t)bh * SEQ * DKH;
  const bf16* Kb = Kk + (size_t)bh * SEQ * DKH;
  const bf16* Vb = Vt + (size_t)bh * DKH * SEQ;

  __shared__ bf16 Ks[2][64 * 64];  // [token][d], XOR-swizzled
  __shared__ bf16 Vs[2][64 * 64];  // [d][token], XOR-swizzled
  __shared__ bf16 Ps[4][32 * 64];  // per-wave P, [q-row][token], XOR-swizzled

  int ldsoff[2];
  const char* ksrc[2];
  const char* vsrc[2];
#pragma unroll
  for (int j = 0; j < 2; ++j) {
    const int L = (w * 64 + lane + 256 * j) * 16;
    const int S = L ^ (((L >> 7) & 7) << 4);
    ldsoff[j] = (w * 64 + 256 * j) * 16;
    ksrc[j] = (const char*)Kb + S;
    vsrc[j] = (const char*)Vb + (size_t)(S >> 7) * (SEQ * 2) + (S & 127);
  }

#define ATTN_STAGE(buf, tt)                                                   \
  _Pragma("unroll")                                                           \
  for (int j = 0; j < 2; ++j) {                                               \
    gload_lds16((char*)Ks[buf] + ldsoff[j], ksrc[j] + (size_t)(tt) * 8192);   \
    gload_lds16((char*)Vs[buf] + ldsoff[j], vsrc[j] + (size_t)(tt) * 128);    \
  }

#define SM_TILE(MASKED)                                                        \
  _Pragma("unroll")                                                            \
  for (int m = 0; m < 2; ++m) {                                                \
    const int qq_ = q0 + m * 16 + r;                                           \
    const int wl_ = m * 16 + r;                                                \
    _Pragma("unroll")                                                          \
    for (int nf = 0; nf < 4; ++nf) {                                           \
      floatx4 p;                                                               \
      _Pragma("unroll")                                                        \
      for (int reg = 0; reg < 4; ++reg) {                                      \
        float pe = exp2f(fmaf(sc[m][nf][reg], 1.442695041f, -17.31234049f));   \
        if (MASKED && (t0 + nf * 16 + g * 4 + reg > qq_)) pe = 0.f;            \
        p[reg] = pe;                                                           \
      }                                                                        \
      l2[m] += p;                                                              \
      unsigned u0, u1;                                                         \
      asm("v_cvt_pk_bf16_f32 %0, %1, %2" : "=v"(u0) : "v"(p[0]), "v"(p[1]));   \
      asm("v_cvt_pk_bf16_f32 %0, %1, %2" : "=v"(u1) : "v"(p[2]), "v"(p[3]));   \
      const int pb = (wl_ * 128 + nf * 32 + g * 8) ^ ((wl_ & 7) << 4);         \
      *(uint2*)((char*)Ps[w] + pb) = make_uint2(u0, u1);                       \
    }                                                                          \
  }

  bf16x8 qf[2][2];
#pragma unroll
  for (int m = 0; m < 2; ++m)
#pragma unroll
    for (int ks = 0; ks < 2; ++ks)
      qf[m][ks] = *(const bf16x8*)(Qb + (size_t)(q0 + m * 16 + r) * DKH + ks * 32 + g * 8);

  floatx4 o[2][4] = {};
  floatx4 l2[2] = {};

  const int nt = 2 * qt + 2;
  ATTN_STAGE(0, 0)
  __syncthreads();
  int cu = 0;
  for (int t = 0; t < nt; ++t) {
    if (t + 1 < nt) ATTN_STAGE(cu ^ 1, t + 1)
    const int t0 = t * 64;

    floatx4 sc[2][4];
    __builtin_amdgcn_s_setprio(1);
#pragma unroll
    for (int nf = 0; nf < 4; ++nf) {
      const int row = nf * 16 + r;
      const int off0 = (row * 128 + g * 16) ^ ((row & 7) << 4);
      bf16x8 kf0 = *(const bf16x8*)((const char*)Ks[cu] + off0);
      bf16x8 kf1 = *(const bf16x8*)((const char*)Ks[cu] + (off0 ^ 64));
      sc[0][nf] = mfma16(kf1, qf[0][1], mfma16(kf0, qf[0][0], floatx4{0.f, 0.f, 0.f, 0.f}));
      sc[1][nf] = mfma16(kf1, qf[1][1], mfma16(kf0, qf[1][0], floatx4{0.f, 0.f, 0.f, 0.f}));
    }
    __builtin_amdgcn_s_setprio(0);

    const bool edge = (t0 + 63 > q0);
    if (edge) {
      SM_TILE(1)
    } else {
      SM_TILE(0)
    }
    asm volatile("s_waitcnt lgkmcnt(0)" ::: "memory");

    bf16x8 pf[2][2];
#pragma unroll
    for (int m = 0; m < 2; ++m)
#pragma unroll
      for (int ks = 0; ks < 2; ++ks) {
        const int prow = m * 16 + r;
        const int ab = (prow * 128 + ks * 64 + g * 16) ^ ((prow & 7) << 4);
        pf[m][ks] = *(const bf16x8*)((const char*)Ps[w] + ab);
      }
    __builtin_amdgcn_s_setprio(1);
#pragma unroll
    for (int nf = 0; nf < 4; ++nf) {
      const int vrow = nf * 16 + r;
      const int vb0 = (vrow * 128 + g * 16) ^ ((vrow & 7) << 4);
      bf16x8 vf0 = *(const bf16x8*)((const char*)Vs[cu] + vb0);
      bf16x8 vf1 = *(const bf16x8*)((const char*)Vs[cu] + (vb0 ^ 64));
#pragma unroll
      for (int m = 0; m < 2; ++m)
        o[m][nf] = mfma16(pf[m][1], vf1, mfma16(pf[m][0], vf0, o[m][nf]));
    }
    __builtin_amdgcn_s_setprio(0);
    __syncthreads();
    cu ^= 1;
  }

  float lsm[2];
#pragma unroll
  for (int m = 0; m < 2; ++m) {
    float ls = l2[m][0] + l2[m][1] + l2[m][2] + l2[m][3];
    ls += __shfl_xor(ls, 16);
    ls += __shfl_xor(ls, 32);
    lsm[m] = ls;
  }
  float linv[2][4];
#pragma unroll
  for (int m = 0; m < 2; ++m)
#pragma unroll
    for (int reg = 0; reg < 4; ++reg)
      linv[m][reg] = 1.f / __shfl(lsm[m], g * 4 + reg);

#pragma unroll
  for (int m = 0; m < 2; ++m)
#pragma unroll
    for (int nf = 0; nf < 4; ++nf)
#pragma unroll
      for (int reg = 0; reg < 4; ++reg) {
        const int s = q0 + m * 16 + g * 4 + reg;
        const int d = nf * 16 + r;
        const float val = o[m][nf][reg] * linv[m][reg];
        AO[((size_t)(b * SEQ + s)) * D_MODEL + h * DKH + d] = (bf16)val;
      }
}

// ---------------- launcher ----------------
extern "C" void kernel_launch(void* const* d_in, const int* in_sizes, int n_in,
                              void* d_out, int out_size, void* d_ws, size_t ws_size,
                              hipStream_t stream) {
  const float* x = (const float*)d_in[0];
  const int* tokpos = (const int*)d_in[1];
  const float* Wq = (const float*)d_in[2];
  const float* Wk = (const float*)d_in[3];
  const float* Wv = (const float*)d_in[4];
  const float* Wo = (const float*)d_in[5];
  float* out = (float*)d_out;

  char* ws = (char*)d_ws;
  if (ws_size < (72ull << 20)) return;  // need 72 MiB scratch

  bf16* xb  = (bf16*)(ws);                     // 16 MiB [8192,1024]
  bf16* wb0 = (bf16*)(ws + (16ull << 20));     // 2 MiB each
  bf16* wb1 = (bf16*)(ws + (18ull << 20));
  bf16* wb2 = (bf16*)(ws + (20ull << 20));
  bf16* wb3 = (bf16*)(ws + (22ull << 20));
  bf16* Qb  = (bf16*)(ws + (24ull << 20));     // 16 MiB [B,H,S,64]
  bf16* Kb  = (bf16*)(ws + (40ull << 20));     // 16 MiB
  bf16* Vt  = (bf16*)(ws + (56ull << 20));     // 16 MiB [B,H,64,S]
  bf16* AO  = (bf16*)(ws);                     // reuse xb region (dead after QKV)
  // RoPE table lives in d_out's head (512 KB); fully overwritten by gemm_out later.
  float2* ropetab = (float2*)d_out;

  cvt_all<<<12544, 256, 0, stream>>>((const float4*)x, (const float4*)Wq,
                                     (const float4*)Wk, (const float4*)Wv,
                                     (const float4*)Wo, (bf16x4*)xb,
                                     (bf16x4*)wb0, (bf16x4*)wb1,
                                     (bf16x4*)wb2, (bf16x4*)wb3,
                                     tokpos, ropetab);

  gemm_proj<<<dim3(8, 64, 2), 256, 0, stream>>>(xb, wb0, wb1, wb2,
                                                Qb, Kb, Vt, ropetab);
  attn128<<<dim3(16, 64), 256, 0, stream>>>(Qb, Kb, Vt, AO);
  gemm_out<<<dim3(8, 64), 256, 0, stream>>>(AO, wb3, out);
}